// Round 1
// baseline (229.935 us; speedup 1.0000x reference)
//
#include <hip/hip_runtime.h>
#include <math.h>

// Batched expm of 4x4 fp32 matrices: out[m] = expm(A[m] * t[m / S]).
// One thread per matrix; all 4x4 state in registers (fully unrolled).
// Scaling-and-squaring identical in structure to the reference:
//   s = clip(ceil(log2(max(||Qt||_inf,1e-30)/0.5)), 0, 16)
//   As = Qt * 2^-s ; P = sum_{k=0..N} As^k/k! ; P = P^(2^s)
// N=10 (reference uses 16; terms >10 are < 1e-11, below fp32 noise).

constexpr int TAYLOR_N = 10;

__global__ void __launch_bounds__(256) expm4_kernel(
    const float* __restrict__ A,
    const float* __restrict__ tvec,
    float* __restrict__ out,
    int M, int S)
{
    const int m = blockIdx.x * 256 + threadIdx.x;
    if (m >= M) return;

    const float t = tvec[m / S];   // wave-uniform (S is a multiple of 64)

    // ---- load A[m] (64 B contiguous) and form Qt = A*t ----
    float a[16];
    const float4* Ap = reinterpret_cast<const float4*>(A) + (size_t)m * 4;
    #pragma unroll
    for (int i = 0; i < 4; ++i) {
        float4 v = Ap[i];
        a[4*i+0] = v.x * t;
        a[4*i+1] = v.y * t;
        a[4*i+2] = v.z * t;
        a[4*i+3] = v.w * t;
    }

    // ---- infinity norm (max abs row sum) ----
    float nrm = 0.0f;
    #pragma unroll
    for (int i = 0; i < 4; ++i) {
        float rs = fabsf(a[4*i+0]) + fabsf(a[4*i+1])
                 + fabsf(a[4*i+2]) + fabsf(a[4*i+3]);
        nrm = fmaxf(nrm, rs);
    }

    // ---- squaring count + scale (matches jnp expression) ----
    float sf = ceilf(log2f(fmaxf(nrm, 1e-30f) * 2.0f));  // log2(nrm/0.5)
    sf = fminf(fmaxf(sf, 0.0f), 16.0f);
    const int   si    = (int)sf;
    const float scale = exp2f(-sf);
    #pragma unroll
    for (int i = 0; i < 16; ++i) a[i] *= scale;          // a = As

    // ---- Taylor: P = I + As + As^2/2! + ... ----
    float P[16], T[16];
    #pragma unroll
    for (int i = 0; i < 16; ++i) { T[i] = a[i]; P[i] = a[i]; }
    P[0] += 1.0f; P[5] += 1.0f; P[10] += 1.0f; P[15] += 1.0f;

    #pragma unroll
    for (int k = 2; k <= TAYLOR_N; ++k) {
        const float rk = 1.0f / (float)k;  // compile-time constant per k
        #pragma unroll
        for (int i = 0; i < 4; ++i) {
            const float t0 = T[4*i+0], t1 = T[4*i+1];
            const float t2 = T[4*i+2], t3 = T[4*i+3];
            #pragma unroll
            for (int j = 0; j < 4; ++j) {
                float v = t0*a[j] + t1*a[4+j] + t2*a[8+j] + t3*a[12+j];
                v *= rk;
                T[4*i+j] = v;
                P[4*i+j] += v;
            }
        }
    }

    // ---- undo scaling: square si times (divergent trip count; wave pays max s) ----
    for (int it = 0; it < si; ++it) {
        float Q[16];
        #pragma unroll
        for (int i = 0; i < 4; ++i) {
            const float p0 = P[4*i+0], p1 = P[4*i+1];
            const float p2 = P[4*i+2], p3 = P[4*i+3];
            #pragma unroll
            for (int j = 0; j < 4; ++j) {
                Q[4*i+j] = p0*P[j] + p1*P[4+j] + p2*P[8+j] + p3*P[12+j];
            }
        }
        #pragma unroll
        for (int i = 0; i < 16; ++i) P[i] = Q[i];
    }

    // ---- store (64 B contiguous) ----
    float4* Op = reinterpret_cast<float4*>(out) + (size_t)m * 4;
    #pragma unroll
    for (int i = 0; i < 4; ++i) {
        float4 v;
        v.x = P[4*i+0]; v.y = P[4*i+1]; v.z = P[4*i+2]; v.w = P[4*i+3];
        Op[i] = v;
    }
}

extern "C" void kernel_launch(void* const* d_in, const int* in_sizes, int n_in,
                              void* d_out, int out_size, void* d_ws, size_t ws_size,
                              hipStream_t stream) {
    const float* A    = (const float*)d_in[0];   // [B, S, 4, 4] fp32
    const float* tvec = (const float*)d_in[1];   // [B] fp32
    float* out        = (float*)d_out;           // [B, S, 4, 4] fp32

    const int B = in_sizes[1];
    const int M = in_sizes[0] / 16;              // total 4x4 matrices
    const int S = M / B;                         // matrices per batch item

    const int threads = 256;
    const int blocks  = (M + threads - 1) / threads;
    expm4_kernel<<<blocks, threads, 0, stream>>>(A, tvec, out, M, S);
}